// Round 2
// baseline (1218.754 us; speedup 1.0000x reference)
//
#include <hip/hip_runtime.h>
#include <math.h>

#define BB 4
#define NN 4096
#define DD 128
#define KK 8
#define NBLK 12

// ---------------- kNN: emulate reference f32 expanded-formula distances ----
// dist[n,m] = (sq[n] - 2*inner) + sq[m], all ops f32 round-to-nearest, no FMA.
// sq[m] = ((x*x + y*y) + z*z). Selection: 8 smallest, ties -> lower index.
__global__ __launch_bounds__(256) void knn_kernel(const float* __restrict__ xyz,
                                                  int* __restrict__ idx) {
    __shared__ float xs[NN], ys[NN], zs[NN], sq[NN];
    const int b = blockIdx.y;
    const float* xb = xyz + (size_t)b * 3 * NN;
    for (int i = threadIdx.x; i < NN; i += 256) {
        float x = xb[i], y = xb[NN + i], z = xb[2 * NN + i];
        xs[i] = x; ys[i] = y; zs[i] = z;
        sq[i] = __fadd_rn(__fadd_rn(__fmul_rn(x, x), __fmul_rn(y, y)),
                          __fmul_rn(z, z));
    }
    __syncthreads();

    const int n = blockIdx.x * 256 + threadIdx.x;
    const float qx = xs[n], qy = ys[n], qz = zs[n], qsq = sq[n];

    float d[KK];
    int id[KK];
#pragma unroll
    for (int j = 0; j < KK; ++j) { d[j] = INFINITY; id[j] = -1; }

    for (int m = 0; m < NN; ++m) {
        float inner = __fadd_rn(__fadd_rn(__fmul_rn(qx, xs[m]),
                                          __fmul_rn(qy, ys[m])),
                                __fmul_rn(qz, zs[m]));
        float dist = __fadd_rn(__fsub_rn(qsq, __fmul_rn(2.0f, inner)), sq[m]);
        if (dist < d[KK - 1]) {          // strict <: ties keep earlier index
            d[KK - 1] = dist; id[KK - 1] = m;
#pragma unroll
            for (int j = KK - 1; j > 0; --j) {
                if (d[j] < d[j - 1]) {   // strict <: stable for equal dists
                    float td = d[j]; d[j] = d[j - 1]; d[j - 1] = td;
                    int ti = id[j]; id[j] = id[j - 1]; id[j - 1] = ti;
                }
            }
        }
    }
    int* op = idx + ((size_t)b * NN + n) * KK;
#pragma unroll
    for (int j = 0; j < KK; ++j) op[j] = id[j];
}

// ---------------- relu + neighbor-sum gather ----------------
// P[b,c,n] = relu(pts[b,c,n]);  G[b,c,n] = sum_k relu(pts[b,c,idx[b,n,k]])
__global__ __launch_bounds__(256) void relu_gather(const float* __restrict__ pts,
                                                   const int* __restrict__ idx,
                                                   float* __restrict__ P,
                                                   float* __restrict__ G) {
    const int b = blockIdx.z;
    const int n = blockIdx.x * 256 + threadIdx.x;
    const int c0 = blockIdx.y * 16;

    int nb[KK];
    const int* ip = idx + ((size_t)b * NN + n) * KK;
#pragma unroll
    for (int k = 0; k < KK; ++k) nb[k] = ip[k];

    for (int c = c0; c < c0 + 16; ++c) {
        const float* row = pts + ((size_t)(b * DD + c)) * NN;
        float v = row[n];
        v = v > 0.0f ? v : 0.0f;
        float s = 0.0f;
#pragma unroll
        for (int k = 0; k < KK; ++k) {
            float u = row[nb[k]];
            s += (u > 0.0f ? u : 0.0f);
        }
        P[((size_t)(b * DD + c)) * NN + n] = v;
        G[((size_t)(b * DD + c)) * NN + n] = s;
    }
}

// ---------------- fused GEMM: out = (W1*P + W2*G)/9 + ptsin ----------------
// C(128 x 4096) = Wcat(128 x 256) * X(256 x 4096),  X = [P ; G]
// block: 64x64 tile, 256 threads, 4x4 microtile
__global__ __launch_bounds__(256) void gemm_block(const float* __restrict__ W1,
                                                  const float* __restrict__ W2,
                                                  const float* __restrict__ P,
                                                  const float* __restrict__ G,
                                                  const float* __restrict__ ptsin,
                                                  float* __restrict__ ptsout) {
    __shared__ float a_s[16][64];   // [k_local][row_local]  (W transposed chunk)
    __shared__ float x_s[16][64];   // [k_local][col_local]

    const int b = blockIdx.z;
    const int rowbase = blockIdx.y * 64;
    const int colbase = blockIdx.x * 64;
    const int tid = threadIdx.x;
    const int tx = tid & 15;        // col group
    const int ty = tid >> 4;        // row group

    float acc[4][4] = {};

    for (int kc = 0; kc < 256; kc += 16) {
        // --- load W chunk: each thread one float4 along k ---
        {
            const int rl = tid >> 2;                 // 0..63 row_local
            const int kl = (tid & 3) << 2;           // 0,4,8,12
            const int kg = kc + kl;
            const float* Wsrc = (kg < 128) ? (W1 + (size_t)(rowbase + rl) * 128 + kg)
                                           : (W2 + (size_t)(rowbase + rl) * 128 + (kg - 128));
            float4 w = *(const float4*)Wsrc;
            a_s[kl + 0][rl] = w.x;
            a_s[kl + 1][rl] = w.y;
            a_s[kl + 2][rl] = w.z;
            a_s[kl + 3][rl] = w.w;
        }
        // --- load X chunk: coalesced over columns ---
        {
            const int col = colbase + (tid & 63);
            const int klb = tid >> 6;                // 0..3
#pragma unroll
            for (int l = 0; l < 4; ++l) {
                const int kl = klb + l * 4;
                const int kg = kc + kl;
                const float* src = (kg < 128)
                    ? (P + ((size_t)(b * DD + kg)) * NN + col)
                    : (G + ((size_t)(b * DD + (kg - 128))) * NN + col);
                x_s[kl][tid & 63] = *src;
            }
        }
        __syncthreads();
#pragma unroll
        for (int k = 0; k < 16; ++k) {
            float4 a = *(const float4*)&a_s[k][ty << 2];
            float4 x = *(const float4*)&x_s[k][tx << 2];
            acc[0][0] += a.x * x.x; acc[0][1] += a.x * x.y; acc[0][2] += a.x * x.z; acc[0][3] += a.x * x.w;
            acc[1][0] += a.y * x.x; acc[1][1] += a.y * x.y; acc[1][2] += a.y * x.z; acc[1][3] += a.y * x.w;
            acc[2][0] += a.z * x.x; acc[2][1] += a.z * x.y; acc[2][2] += a.z * x.z; acc[2][3] += a.z * x.w;
            acc[3][0] += a.w * x.x; acc[3][1] += a.w * x.y; acc[3][2] += a.w * x.z; acc[3][3] += a.w * x.w;
        }
        __syncthreads();
    }

    const float inv = 1.0f / 9.0f;
#pragma unroll
    for (int i = 0; i < 4; ++i) {
        const int row = rowbase + (ty << 2) + i;
        const size_t off = ((size_t)(b * DD + row)) * NN + colbase + (tx << 2);
        float4 old = *(const float4*)(ptsin + off);
        float4 o;
        o.x = acc[i][0] * inv + old.x;
        o.y = acc[i][1] * inv + old.y;
        o.z = acc[i][2] * inv + old.z;
        o.w = acc[i][3] * inv + old.w;
        *(float4*)(ptsout + off) = o;
    }
}

// ---------------- final unpool head ----------------
__global__ __launch_bounds__(256) void final_xyz(const float* __restrict__ P,
                                                 const float* __restrict__ G,
                                                 const float* __restrict__ wc,
                                                 const float* __restrict__ wn,
                                                 const float* __restrict__ xyz,
                                                 float* __restrict__ out) {
    __shared__ float wcs[6][128], wns[6][128];
    const int b = blockIdx.y;
    for (int i = threadIdx.x; i < 6 * 128; i += 256) {
        wcs[i / 128][i % 128] = wc[i];
        wns[i / 128][i % 128] = wn[i];
    }
    __syncthreads();

    const int n = blockIdx.x * 256 + threadIdx.x;
    float acc[6] = {};
    for (int k = 0; k < 128; ++k) {
        float pv = P[((size_t)(b * DD + k)) * NN + n];
        float gv = G[((size_t)(b * DD + k)) * NN + n];
#pragma unroll
        for (int o = 0; o < 6; ++o) acc[o] += wcs[o][k] * pv + wns[o][k] * gv;
    }
    const float inv = 1.0f / 9.0f;
#pragma unroll
    for (int d = 0; d < 3; ++d) {
        float xv = xyz[((size_t)b * 3 + d) * NN + n];
        out[(((size_t)b * 3 + d) * 2 + 0) * NN + n] = acc[d * 2 + 0] * inv + xv;
        out[(((size_t)b * 3 + d) * 2 + 1) * NN + n] = acc[d * 2 + 1] * inv + xv;
    }
}

extern "C" void kernel_launch(void* const* d_in, const int* in_sizes, int n_in,
                              void* d_out, int out_size, void* d_ws, size_t ws_size,
                              hipStream_t stream) {
    const float* xyz    = (const float*)d_in[0];
    const float* points = (const float*)d_in[1];
    const float* w1     = (const float*)d_in[2];
    const float* w2     = (const float*)d_in[3];
    const float* wc     = (const float*)d_in[4];
    const float* wn     = (const float*)d_in[5];
    float* out = (float*)d_out;

    const size_t feat = (size_t)BB * DD * NN;      // 2,097,152 floats
    char* ws = (char*)d_ws;
    int*   idx = (int*)ws;                          // B*N*K ints (512 KB)
    float* P   = (float*)(ws + (size_t)BB * NN * KK * sizeof(int));
    float* G   = P + feat;
    float* p0  = G + feat;
    float* p1  = p0 + feat;

    hipMemcpyAsync(p0, points, feat * sizeof(float), hipMemcpyDeviceToDevice, stream);

    knn_kernel<<<dim3(NN / 256, BB), 256, 0, stream>>>(xyz, idx);

    float* cur = p0;
    float* nxt = p1;
    for (int i = 0; i < NBLK; ++i) {
        relu_gather<<<dim3(NN / 256, 8, BB), 256, 0, stream>>>(cur, idx, P, G);
        float* dst = (i == NBLK - 1) ? (out + (size_t)BB * 3 * 2 * NN) : nxt;
        gemm_block<<<dim3(NN / 64, 2, BB), 256, 0, stream>>>(
            w1 + (size_t)i * DD * DD, w2 + (size_t)i * DD * DD, P, G, cur, dst);
        float* t = cur; cur = nxt; nxt = t;
    }

    final_xyz<<<dim3(NN / 256, BB), 256, 0, stream>>>(P, G, wc, wn, xyz, out);
}

// Round 3
// 711.366 us; speedup vs baseline: 1.7133x; 1.7133x over previous
//
#include <hip/hip_runtime.h>
#include <math.h>

#define BB 4
#define NN 4096
#define DD 128
#define KK 8
#define NBLK 12

// ---------------- kNN: wave-per-query, emulated reference f32 distances ----
// dist[n,m] = (sq[n] - 2*inner) + sq[m], all ops f32 RN, no FMA.
// Each wave owns one query; each lane scans 64 candidates (interleaved float4
// chunks), keeps a stable local top-8; 8-step shuffle merge extracts the
// global 8 smallest by (dist, idx) — matches top_k stable tie-breaking.
__global__ __launch_bounds__(512) void knn_kernel(const float* __restrict__ xyz,
                                                  int* __restrict__ idx) {
    __shared__ float xs[NN], ys[NN], zs[NN], sq[NN];
    const int b = blockIdx.y;
    const float* xb = xyz + (size_t)b * 3 * NN;
    for (int i = threadIdx.x; i < NN; i += 512) {
        float x = xb[i], y = xb[NN + i], z = xb[2 * NN + i];
        xs[i] = x; ys[i] = y; zs[i] = z;
        sq[i] = __fadd_rn(__fadd_rn(__fmul_rn(x, x), __fmul_rn(y, y)),
                          __fmul_rn(z, z));
    }
    __syncthreads();

    const int wave = threadIdx.x >> 6;
    const int lane = threadIdx.x & 63;
    const int n = blockIdx.x * 8 + wave;           // query index
    const float qx = xs[n], qy = ys[n], qz = zs[n], qsq = sq[n];

    float d[KK];
    int id[KK];
#pragma unroll
    for (int j = 0; j < KK; ++j) { d[j] = INFINITY; id[j] = -1; }

    for (int j = 0; j < NN / 256; ++j) {           // 16 float4 chunks per lane
        const int m0 = j * 256 + lane * 4;
        const float4 vx = *(const float4*)&xs[m0];
        const float4 vy = *(const float4*)&ys[m0];
        const float4 vz = *(const float4*)&zs[m0];
        const float4 vq = *(const float4*)&sq[m0];
#pragma unroll
        for (int e = 0; e < 4; ++e) {
            const float cx = (&vx.x)[e], cy = (&vy.x)[e], cz = (&vz.x)[e];
            const float cq = (&vq.x)[e];
            float inner = __fadd_rn(__fadd_rn(__fmul_rn(qx, cx),
                                              __fmul_rn(qy, cy)),
                                    __fmul_rn(qz, cz));
            float dist = __fadd_rn(__fsub_rn(qsq, __fmul_rn(2.0f, inner)), cq);
            if (dist < d[KK - 1]) {                // strict <: stable
                d[KK - 1] = dist; id[KK - 1] = m0 + e;
#pragma unroll
                for (int t = KK - 1; t > 0; --t) {
                    if (d[t] < d[t - 1]) {
                        float td = d[t]; d[t] = d[t - 1]; d[t - 1] = td;
                        int ti = id[t]; id[t] = id[t - 1]; id[t - 1] = ti;
                    }
                }
            }
        }
    }

    // cross-lane merge: 8x extract global min by (dist, then idx)
    int out[KK];
#pragma unroll
    for (int it = 0; it < KK; ++it) {
        float hd = d[0];
        int hi = id[0];
#pragma unroll
        for (int s = 32; s; s >>= 1) {
            float od = __shfl_xor(hd, s, 64);
            int oi = __shfl_xor(hi, s, 64);
            if (od < hd || (od == hd && oi < hi)) { hd = od; hi = oi; }
        }
        out[it] = hi;
        if (hd == d[0] && hi == id[0]) {           // winner lane: pop head
#pragma unroll
            for (int t = 0; t < KK - 1; ++t) { d[t] = d[t + 1]; id[t] = id[t + 1]; }
            d[KK - 1] = INFINITY; id[KK - 1] = -1;
        }
    }

    if (lane == 0) {
        int* op = idx + ((size_t)b * NN + n) * KK;
        *(int4*)op       = make_int4(out[0], out[1], out[2], out[3]);
        *(int4*)(op + 4) = make_int4(out[4], out[5], out[6], out[7]);
    }
}

// ---------------- relu + neighbor-sum gather ----------------
__global__ __launch_bounds__(256) void relu_gather(const float* __restrict__ pts,
                                                   const int* __restrict__ idx,
                                                   float* __restrict__ P,
                                                   float* __restrict__ G) {
    const int b = blockIdx.z;
    const int n = blockIdx.x * 256 + threadIdx.x;
    const int c0 = blockIdx.y * 16;

    int nb[KK];
    const int* ip = idx + ((size_t)b * NN + n) * KK;
#pragma unroll
    for (int k = 0; k < KK; ++k) nb[k] = ip[k];

    for (int c = c0; c < c0 + 16; ++c) {
        const float* row = pts + ((size_t)(b * DD + c)) * NN;
        float v = row[n];
        v = v > 0.0f ? v : 0.0f;
        float s = 0.0f;
#pragma unroll
        for (int k = 0; k < KK; ++k) {
            float u = row[nb[k]];
            s += (u > 0.0f ? u : 0.0f);
        }
        P[((size_t)(b * DD + c)) * NN + n] = v;
        G[((size_t)(b * DD + c)) * NN + n] = s;
    }
}

// ---------------- fused GEMM: out = (W1*P + W2*G)/9 + ptsin ----------------
__global__ __launch_bounds__(256) void gemm_block(const float* __restrict__ W1,
                                                  const float* __restrict__ W2,
                                                  const float* __restrict__ P,
                                                  const float* __restrict__ G,
                                                  const float* __restrict__ ptsin,
                                                  float* __restrict__ ptsout) {
    __shared__ float a_s[16][64];
    __shared__ float x_s[16][64];

    const int b = blockIdx.z;
    const int rowbase = blockIdx.y * 64;
    const int colbase = blockIdx.x * 64;
    const int tid = threadIdx.x;
    const int tx = tid & 15;
    const int ty = tid >> 4;

    float acc[4][4] = {};

    for (int kc = 0; kc < 256; kc += 16) {
        {
            const int rl = tid >> 2;
            const int kl = (tid & 3) << 2;
            const int kg = kc + kl;
            const float* Wsrc = (kg < 128) ? (W1 + (size_t)(rowbase + rl) * 128 + kg)
                                           : (W2 + (size_t)(rowbase + rl) * 128 + (kg - 128));
            float4 w = *(const float4*)Wsrc;
            a_s[kl + 0][rl] = w.x;
            a_s[kl + 1][rl] = w.y;
            a_s[kl + 2][rl] = w.z;
            a_s[kl + 3][rl] = w.w;
        }
        {
            const int col = colbase + (tid & 63);
            const int klb = tid >> 6;
#pragma unroll
            for (int l = 0; l < 4; ++l) {
                const int kl = klb + l * 4;
                const int kg = kc + kl;
                const float* src = (kg < 128)
                    ? (P + ((size_t)(b * DD + kg)) * NN + col)
                    : (G + ((size_t)(b * DD + (kg - 128))) * NN + col);
                x_s[kl][tid & 63] = *src;
            }
        }
        __syncthreads();
#pragma unroll
        for (int k = 0; k < 16; ++k) {
            float4 a = *(const float4*)&a_s[k][ty << 2];
            float4 x = *(const float4*)&x_s[k][tx << 2];
            acc[0][0] += a.x * x.x; acc[0][1] += a.x * x.y; acc[0][2] += a.x * x.z; acc[0][3] += a.x * x.w;
            acc[1][0] += a.y * x.x; acc[1][1] += a.y * x.y; acc[1][2] += a.y * x.z; acc[1][3] += a.y * x.w;
            acc[2][0] += a.z * x.x; acc[2][1] += a.z * x.y; acc[2][2] += a.z * x.z; acc[2][3] += a.z * x.w;
            acc[3][0] += a.w * x.x; acc[3][1] += a.w * x.y; acc[3][2] += a.w * x.z; acc[3][3] += a.w * x.w;
        }
        __syncthreads();
    }

    const float inv = 1.0f / 9.0f;
#pragma unroll
    for (int i = 0; i < 4; ++i) {
        const int row = rowbase + (ty << 2) + i;
        const size_t off = ((size_t)(b * DD + row)) * NN + colbase + (tx << 2);
        float4 old = *(const float4*)(ptsin + off);
        float4 o;
        o.x = acc[i][0] * inv + old.x;
        o.y = acc[i][1] * inv + old.y;
        o.z = acc[i][2] * inv + old.z;
        o.w = acc[i][3] * inv + old.w;
        *(float4*)(ptsout + off) = o;
    }
}

// ---------------- final unpool head ----------------
__global__ __launch_bounds__(256) void final_xyz(const float* __restrict__ P,
                                                 const float* __restrict__ G,
                                                 const float* __restrict__ wc,
                                                 const float* __restrict__ wn,
                                                 const float* __restrict__ xyz,
                                                 float* __restrict__ out) {
    __shared__ float wcs[6][128], wns[6][128];
    const int b = blockIdx.y;
    for (int i = threadIdx.x; i < 6 * 128; i += 256) {
        wcs[i / 128][i % 128] = wc[i];
        wns[i / 128][i % 128] = wn[i];
    }
    __syncthreads();

    const int n = blockIdx.x * 256 + threadIdx.x;
    float acc[6] = {};
    for (int k = 0; k < 128; ++k) {
        float pv = P[((size_t)(b * DD + k)) * NN + n];
        float gv = G[((size_t)(b * DD + k)) * NN + n];
#pragma unroll
        for (int o = 0; o < 6; ++o) acc[o] += wcs[o][k] * pv + wns[o][k] * gv;
    }
    const float inv = 1.0f / 9.0f;
#pragma unroll
    for (int d = 0; d < 3; ++d) {
        float xv = xyz[((size_t)b * 3 + d) * NN + n];
        out[(((size_t)b * 3 + d) * 2 + 0) * NN + n] = acc[d * 2 + 0] * inv + xv;
        out[(((size_t)b * 3 + d) * 2 + 1) * NN + n] = acc[d * 2 + 1] * inv + xv;
    }
}

extern "C" void kernel_launch(void* const* d_in, const int* in_sizes, int n_in,
                              void* d_out, int out_size, void* d_ws, size_t ws_size,
                              hipStream_t stream) {
    const float* xyz    = (const float*)d_in[0];
    const float* points = (const float*)d_in[1];
    const float* w1     = (const float*)d_in[2];
    const float* w2     = (const float*)d_in[3];
    const float* wc     = (const float*)d_in[4];
    const float* wn     = (const float*)d_in[5];
    float* out = (float*)d_out;

    const size_t feat = (size_t)BB * DD * NN;
    char* ws = (char*)d_ws;
    int*   idx = (int*)ws;
    float* P   = (float*)(ws + (size_t)BB * NN * KK * sizeof(int));
    float* G   = P + feat;
    float* p0  = G + feat;
    float* p1  = p0 + feat;

    knn_kernel<<<dim3(NN / 8, BB), 512, 0, stream>>>(xyz, idx);

    const float* cur = points;   // iteration 0 reads inputs directly
    float* nxt = p0;
    float* other = p1;
    for (int i = 0; i < NBLK; ++i) {
        relu_gather<<<dim3(NN / 256, 8, BB), 256, 0, stream>>>(cur, idx, P, G);
        float* dst = (i == NBLK - 1) ? (out + (size_t)BB * 3 * 2 * NN) : nxt;
        gemm_block<<<dim3(NN / 64, 2, BB), 256, 0, stream>>>(
            w1 + (size_t)i * DD * DD, w2 + (size_t)i * DD * DD, P, G, cur, dst);
        cur = dst;
        float* t = nxt; nxt = other; other = t;
        if (i == 0) other = p0;  // after first iter, ping-pong p0/p1
    }

    final_xyz<<<dim3(NN / 256, BB), 256, 0, stream>>>(P, G, wc, wn, xyz, out);
}

// Round 4
// 371.558 us; speedup vs baseline: 3.2801x; 1.9145x over previous
//
#include <hip/hip_runtime.h>
#include <math.h>

#define BB 4
#define NN 4096
#define DD 128
#define KK 8
#define NBLK 12

typedef __attribute__((ext_vector_type(8))) short short8;
typedef __attribute__((ext_vector_type(4))) float f32x4;

__device__ inline ushort bf16_rn(float x) {
    uint u = __float_as_uint(x);
    u = (u + 0x7FFFu + ((u >> 16) & 1u)) >> 16;
    return (ushort)u;
}
__device__ inline float bf16_f(ushort h) { return __uint_as_float(((uint)h) << 16); }

// ---------------- kNN (unchanged from R3: passes, 112us) ----------------
__global__ __launch_bounds__(512) void knn_kernel(const float* __restrict__ xyz,
                                                  int* __restrict__ idx) {
    __shared__ float xs[NN], ys[NN], zs[NN], sq[NN];
    const int b = blockIdx.y;
    const float* xb = xyz + (size_t)b * 3 * NN;
    for (int i = threadIdx.x; i < NN; i += 512) {
        float x = xb[i], y = xb[NN + i], z = xb[2 * NN + i];
        xs[i] = x; ys[i] = y; zs[i] = z;
        sq[i] = __fadd_rn(__fadd_rn(__fmul_rn(x, x), __fmul_rn(y, y)),
                          __fmul_rn(z, z));
    }
    __syncthreads();

    const int wave = threadIdx.x >> 6;
    const int lane = threadIdx.x & 63;
    const int n = blockIdx.x * 8 + wave;
    const float qx = xs[n], qy = ys[n], qz = zs[n], qsq = sq[n];

    float d[KK];
    int id[KK];
#pragma unroll
    for (int j = 0; j < KK; ++j) { d[j] = INFINITY; id[j] = -1; }

    for (int j = 0; j < NN / 256; ++j) {
        const int m0 = j * 256 + lane * 4;
        const float4 vx = *(const float4*)&xs[m0];
        const float4 vy = *(const float4*)&ys[m0];
        const float4 vz = *(const float4*)&zs[m0];
        const float4 vq = *(const float4*)&sq[m0];
#pragma unroll
        for (int e = 0; e < 4; ++e) {
            const float cx = (&vx.x)[e], cy = (&vy.x)[e], cz = (&vz.x)[e];
            const float cq = (&vq.x)[e];
            float inner = __fadd_rn(__fadd_rn(__fmul_rn(qx, cx),
                                              __fmul_rn(qy, cy)),
                                    __fmul_rn(qz, cz));
            float dist = __fadd_rn(__fsub_rn(qsq, __fmul_rn(2.0f, inner)), cq);
            if (dist < d[KK - 1]) {
                d[KK - 1] = dist; id[KK - 1] = m0 + e;
#pragma unroll
                for (int t = KK - 1; t > 0; --t) {
                    if (d[t] < d[t - 1]) {
                        float td = d[t]; d[t] = d[t - 1]; d[t - 1] = td;
                        int ti = id[t]; id[t] = id[t - 1]; id[t - 1] = ti;
                    }
                }
            }
        }
    }

    int out[KK];
#pragma unroll
    for (int it = 0; it < KK; ++it) {
        float hd = d[0];
        int hi = id[0];
#pragma unroll
        for (int s = 32; s; s >>= 1) {
            float od = __shfl_xor(hd, s, 64);
            int oi = __shfl_xor(hi, s, 64);
            if (od < hd || (od == hd && oi < hi)) { hd = od; hi = oi; }
        }
        out[it] = hi;
        if (hd == d[0] && hi == id[0]) {
#pragma unroll
            for (int t = 0; t < KK - 1; ++t) { d[t] = d[t + 1]; id[t] = id[t + 1]; }
            d[KK - 1] = INFINITY; id[KK - 1] = -1;
        }
    }

    if (lane == 0) {
        int* op = idx + ((size_t)b * NN + n) * KK;
        *(int4*)op       = make_int4(out[0], out[1], out[2], out[3]);
        *(int4*)(op + 4) = make_int4(out[4], out[5], out[6], out[7]);
    }
}

// ---------------- weight prep: Wcat = [W1 | W2] split to bf16 hi/lo -------
__global__ __launch_bounds__(256) void prep_w(const float* __restrict__ w1,
                                              const float* __restrict__ w2,
                                              ushort* __restrict__ whi,
                                              ushort* __restrict__ wlo) {
    const int e = blockIdx.x * 256 + threadIdx.x;     // l*32768 + r*256 + k
    const int l = e >> 15;
    const int rem = e & 32767;
    const int r = rem >> 8;
    const int k = rem & 255;
    float w = (k < 128) ? w1[((size_t)l * 128 + r) * 128 + k]
                        : w2[((size_t)l * 128 + r) * 128 + (k - 128)];
    ushort h = bf16_rn(w);
    whi[e] = h;
    wlo[e] = bf16_rn(w - bf16_f(h));
}

// ---------------- initial transpose: ptsT[b][n][c] = points[b][c][n] ------
__global__ __launch_bounds__(256) void transpose_pts(const float* __restrict__ pts,
                                                     float* __restrict__ ptsT) {
    __shared__ float t[32][33];
    const int b = blockIdx.z;
    const int c0 = blockIdx.y * 32;
    const int n0 = blockIdx.x * 32;
    const int tx = threadIdx.x & 31;
    const int ty = threadIdx.x >> 5;
#pragma unroll
    for (int q = 0; q < 4; ++q)
        t[ty + 8 * q][tx] = pts[((size_t)b * DD + c0 + ty + 8 * q) * NN + n0 + tx];
    __syncthreads();
#pragma unroll
    for (int q = 0; q < 4; ++q)
        ptsT[((size_t)b * NN + n0 + ty + 8 * q) * DD + c0 + tx] = t[tx][ty + 8 * q];
}

// ---------------- fused: relu+gather -> split bf16 -> MFMA -> residual ----
// block: 64 cols x 128 rows, 256 threads (4 waves).
// LDS: XT_hi[64][256] bf16 + XT_lo[64][256] bf16, granule-XOR swizzled:
//   elem (n,k) at byte n*512 + (((k>>3) ^ (n&7))<<4) + (k&7)*2
__global__ __launch_bounds__(256) void fused_block(const float* __restrict__ ptsT_in,
                                                   const int* __restrict__ idx,
                                                   const ushort* __restrict__ whi,
                                                   const ushort* __restrict__ wlo,
                                                   float* __restrict__ ptsT_out,
                                                   float* __restrict__ out_std,
                                                   float* __restrict__ PT,
                                                   float* __restrict__ GT,
                                                   const int last) {
    __shared__ __align__(16) char xt[65536];
    char* xt_hi = xt;
    char* xt_lo = xt + 32768;

    const int b = blockIdx.y;
    const int colbase = blockIdx.x * 64;
    const int w = threadIdx.x >> 6;
    const int lane = threadIdx.x & 63;

    const float* baseT = ptsT_in + (size_t)b * NN * DD;

    // ---- phase A: gather (coalesced 512B row reads), split, stage to LDS
    {
        // preload the wave's 16 idx rows: 128 ints -> int2 per lane
        const int* ibase = idx + ((size_t)b * NN + colbase + w * 16) * KK;
        int2 iv = *(const int2*)(ibase + lane * 2);

        for (int i = 0; i < 16; ++i) {
            const int n_loc = w * 16 + i;
            const int n = colbase + n_loc;
            int nb[KK];
#pragma unroll
            for (int j = 0; j < KK; ++j)
                nb[j] = __shfl((j & 1) ? iv.y : iv.x, i * 4 + (j >> 1), 64);

            const float2 c2 = *(const float2*)(baseT + (size_t)n * DD + 2 * lane);
            float gx = 0.0f, gy = 0.0f;
#pragma unroll
            for (int j = 0; j < KK; ++j) {
                const float2 u = *(const float2*)(baseT + (size_t)nb[j] * DD + 2 * lane);
                gx += fmaxf(u.x, 0.0f);
                gy += fmaxf(u.y, 0.0f);
            }
            const float px = fmaxf(c2.x, 0.0f);
            const float py = fmaxf(c2.y, 0.0f);

            // split to bf16 hi/lo
            ushort phx = bf16_rn(px), phy = bf16_rn(py);
            ushort plx = bf16_rn(px - bf16_f(phx)), ply = bf16_rn(py - bf16_f(phy));
            ushort ghx = bf16_rn(gx), ghy = bf16_rn(gy);
            ushort glx = bf16_rn(gx - bf16_f(ghx)), gly = bf16_rn(gy - bf16_f(ghy));

            const int kP = 2 * lane;
            const int kG = 128 + 2 * lane;
            const int byP = n_loc * 512 + ((((kP >> 3) ^ (n_loc & 7))) << 4) + ((kP & 7) << 1);
            const int byG = n_loc * 512 + ((((kG >> 3) ^ (n_loc & 7))) << 4) + ((kG & 7) << 1);
            *(uint*)(xt_hi + byP) = (uint)phx | ((uint)phy << 16);
            *(uint*)(xt_lo + byP) = (uint)plx | ((uint)ply << 16);
            *(uint*)(xt_hi + byG) = (uint)ghx | ((uint)ghy << 16);
            *(uint*)(xt_lo + byG) = (uint)glx | ((uint)gly << 16);

            if (last) {   // dump P,G (fp32, [n][c] layout) for the head kernel
                *(float2*)(PT + ((size_t)b * NN + n) * DD + 2 * lane) = make_float2(px, py);
                *(float2*)(GT + ((size_t)b * NN + n) * DD + 2 * lane) = make_float2(gx, gy);
            }
        }
    }
    __syncthreads();

    // ---- phase B: MFMA. wave w: rows w*32..w*32+31 (2 rowtiles), 4 ntiles
    const int ln15 = lane & 15;
    const int kl = lane >> 4;

    f32x4 acc[2][4] = {};
#pragma unroll
    for (int pass = 0; pass < 3; ++pass) {
        const ushort* Wp = (pass == 2) ? wlo : whi;
        const char* Xp = (pass == 1) ? xt_lo : xt_hi;
#pragma unroll
        for (int ks = 0; ks < 8; ++ks) {
            short8 a[2];
#pragma unroll
            for (int rt = 0; rt < 2; ++rt) {
                const int row = w * 32 + rt * 16 + ln15;
                a[rt] = *(const short8*)(Wp + (size_t)row * 256 + ks * 32 + kl * 8);
            }
            short8 bf[4];
#pragma unroll
            for (int nt = 0; nt < 4; ++nt) {
                const int n_loc = nt * 16 + ln15;
                const int by = n_loc * 512 + (((ks * 4 + kl) ^ (n_loc & 7)) << 4);
                bf[nt] = *(const short8*)(Xp + by);
            }
#pragma unroll
            for (int rt = 0; rt < 2; ++rt)
#pragma unroll
                for (int nt = 0; nt < 4; ++nt)
                    acc[rt][nt] = __builtin_amdgcn_mfma_f32_16x16x32_bf16(
                        a[rt], bf[nt], acc[rt][nt], 0, 0, 0);
        }
    }

    // ---- phase C: epilogue: out = acc/9 + shortcut
    const float inv = 1.0f / 9.0f;
#pragma unroll
    for (int rt = 0; rt < 2; ++rt) {
#pragma unroll
        for (int nt = 0; nt < 4; ++nt) {
            const int row = w * 32 + rt * 16 + (lane >> 4) * 4;
            const int n = colbase + nt * 16 + ln15;
            const float4 sc = *(const float4*)(baseT + (size_t)n * DD + row);
            float v0 = acc[rt][nt][0] * inv + sc.x;
            float v1 = acc[rt][nt][1] * inv + sc.y;
            float v2 = acc[rt][nt][2] * inv + sc.z;
            float v3 = acc[rt][nt][3] * inv + sc.w;
            if (!last) {
                *(float4*)(ptsT_out + ((size_t)b * NN + n) * DD + row) =
                    make_float4(v0, v1, v2, v3);
            } else {     // final points -> d_out in standard [b][c][n] layout
                out_std[((size_t)b * DD + row + 0) * NN + n] = v0;
                out_std[((size_t)b * DD + row + 1) * NN + n] = v1;
                out_std[((size_t)b * DD + row + 2) * NN + n] = v2;
                out_std[((size_t)b * DD + row + 3) * NN + n] = v3;
            }
        }
    }
}

// ---------------- final unpool head (reads PT/GT in [n][c] layout) --------
__global__ __launch_bounds__(256) void final_head(const float* __restrict__ PT,
                                                  const float* __restrict__ GT,
                                                  const float* __restrict__ wc,
                                                  const float* __restrict__ wn,
                                                  const float* __restrict__ xyz,
                                                  float* __restrict__ out) {
    __shared__ float wcs[6][128], wns[6][128];
    const int b = blockIdx.y;
    for (int i = threadIdx.x; i < 6 * 128; i += 256) {
        wcs[i >> 7][i & 127] = wc[i];
        wns[i >> 7][i & 127] = wn[i];
    }
    __syncthreads();

    const int w = threadIdx.x >> 6;
    const int lane = threadIdx.x & 63;
    const float inv = 1.0f / 9.0f;

    for (int i = 0; i < 16; ++i) {
        const int n = blockIdx.x * 64 + w * 16 + i;
        const float2 p2 = *(const float2*)(PT + ((size_t)b * NN + n) * DD + 2 * lane);
        const float2 g2 = *(const float2*)(GT + ((size_t)b * NN + n) * DD + 2 * lane);
        float s[6];
#pragma unroll
        for (int o = 0; o < 6; ++o) {
            s[o] = p2.x * wcs[o][2 * lane] + p2.y * wcs[o][2 * lane + 1]
                 + g2.x * wns[o][2 * lane] + g2.y * wns[o][2 * lane + 1];
        }
#pragma unroll
        for (int st = 32; st; st >>= 1) {
#pragma unroll
            for (int o = 0; o < 6; ++o) s[o] += __shfl_xor(s[o], st, 64);
        }
        if (lane < 6) {
            const int dd = lane >> 1, h = lane & 1;
            const float xv = xyz[((size_t)b * 3 + dd) * NN + n];
            out[(((size_t)b * 3 + dd) * 2 + h) * NN + n] = s[lane] * inv + xv;
        }
    }
}

extern "C" void kernel_launch(void* const* d_in, const int* in_sizes, int n_in,
                              void* d_out, int out_size, void* d_ws, size_t ws_size,
                              hipStream_t stream) {
    const float* xyz    = (const float*)d_in[0];
    const float* points = (const float*)d_in[1];
    const float* w1     = (const float*)d_in[2];
    const float* w2     = (const float*)d_in[3];
    const float* wc     = (const float*)d_in[4];
    const float* wn     = (const float*)d_in[5];
    float* out = (float*)d_out;

    const size_t feat = (size_t)BB * DD * NN;          // 2,097,152 floats
    char* ws = (char*)d_ws;
    int*    idx  = (int*)ws;                            // 512 KB
    ushort* whi  = (ushort*)(ws + 524288);              // 768 KB
    ushort* wlo  = (ushort*)(ws + 524288 + 786432);     // 768 KB
    float*  pT0  = (float*)(ws + 524288 + 2 * 786432);  // 8 MB
    float*  pT1  = pT0 + feat;                          // 8 MB
    float*  PT   = pT1 + feat;                          // 8 MB
    float*  GT   = PT + feat;                           // 8 MB

    knn_kernel<<<dim3(NN / 8, BB), 512, 0, stream>>>(xyz, idx);
    prep_w<<<dim3(12 * 128 * 256 / 256), 256, 0, stream>>>(w1, w2, whi, wlo);
    transpose_pts<<<dim3(NN / 32, DD / 32, BB), 256, 0, stream>>>(points, pT0);

    float* out_pts = out + (size_t)BB * 3 * 2 * NN;
    float* bufs[2] = {pT0, pT1};
    for (int i = 0; i < NBLK; ++i) {
        const int last = (i == NBLK - 1);
        fused_block<<<dim3(NN / 64, BB), 256, 0, stream>>>(
            bufs[i & 1], idx, whi + (size_t)i * 32768, wlo + (size_t)i * 32768,
            bufs[(i + 1) & 1], out_pts, PT, GT, last);
    }

    final_head<<<dim3(NN / 64, BB), 256, 0, stream>>>(PT, GT, wc, wn, xyz, out);
}